// Round 5
// baseline (309.106 us; speedup 1.0000x reference)
//
#include <hip/hip_runtime.h>
#include <math.h>

constexpr int B_  = 128;
constexpr int A_  = 2048;
constexpr int C_  = 128;
constexpr int H_  = 512;
constexpr int S_  = 3;
constexpr int NR_ = 2;
constexpr int PR_ = C_ + 3 + S_;      // 134
constexpr int PW_ = 3 * C_ + 3 + S_;  // 390

typedef float vfloat4 __attribute__((ext_vector_type(4)));

__device__ __forceinline__ float sigmoidf_(float x) { return 1.0f / (1.0f + expf(-x)); }
__device__ __forceinline__ float softplusf_(float x) {
  return fmaxf(x, 0.0f) + log1pf(expf(-fabsf(x)));
}

__device__ __forceinline__ float waveReduceSum(float v) {
#pragma unroll
  for (int off = 32; off; off >>= 1) v += __shfl_xor(v, off, 64);
  return v;
}
__device__ __forceinline__ float waveReduceMax(float v) {
#pragma unroll
  for (int off = 32; off; off >>= 1) v = fmaxf(v, __shfl_xor(v, off, 64));
  return v;
}

// ---------------------------------------------------------------------------
// Kernel 1: projections (one wave per TWO adjacent outputs), plus zeroing of
// rv (atomicAdd target) and the 256 pair-sync flags.
// ---------------------------------------------------------------------------
__global__ __launch_bounds__(256) void proj_kernel(
    const float* __restrict__ h, const float* __restrict__ Wr,
    const float* __restrict__ br, const float* __restrict__ Ww,
    const float* __restrict__ bw, float* __restrict__ pr, float* __restrict__ pw,
    float* __restrict__ rv, int* __restrict__ flags) {
  constexpr int NPR = NR_ * B_ * PR_;   // 34304
  constexpr int NPW = B_ * PW_;         // 49920
  int gid = blockIdx.x * blockDim.x + threadIdx.x;
  if (gid < NR_ * B_ * C_) rv[gid] = 0.0f;
  if (gid < 256) flags[gid] = 0;
  int wave = gid >> 6;
  int lane = threadIdx.x & 63;
  int out0 = wave * 2;
  const float* w0row;
  const float* w1row;
  const float* hrow;
  float bias0, bias1;
  float* outp;
  if (out0 < NPR) {
    int r = out0 / (B_ * PR_);
    int rem = out0 - r * (B_ * PR_);
    int b = rem / PR_;
    int p = rem - b * PR_;
    w0row = Wr + (size_t)(r * PR_ + p) * H_;
    w1row = w0row + H_;
    hrow = h + (size_t)b * H_;
    bias0 = br[r * PR_ + p];
    bias1 = br[r * PR_ + p + 1];
    outp = pr + out0;
  } else {
    int w2 = out0 - NPR;
    if (w2 >= NPW) return;
    int b = w2 / PW_;
    int p = w2 - b * PW_;
    w0row = Ww + (size_t)p * H_;
    w1row = w0row + H_;
    hrow = h + (size_t)b * H_;
    bias0 = bw[p];
    bias1 = bw[p + 1];
    outp = pw + w2;
  }
  const float4* h4 = (const float4*)hrow;
  const float4* wa4 = (const float4*)w0row;
  const float4* wb4 = (const float4*)w1row;
  float4 a0 = h4[(lane << 1)];
  float4 a1 = h4[(lane << 1) + 1];
  float4 b0 = wa4[(lane << 1)];
  float4 b1 = wa4[(lane << 1) + 1];
  float4 c0 = wb4[(lane << 1)];
  float4 c1 = wb4[(lane << 1) + 1];
  float acc0 = a0.x * b0.x;
  acc0 = fmaf(a0.y, b0.y, acc0);
  acc0 = fmaf(a0.z, b0.z, acc0);
  acc0 = fmaf(a0.w, b0.w, acc0);
  acc0 = fmaf(a1.x, b1.x, acc0);
  acc0 = fmaf(a1.y, b1.y, acc0);
  acc0 = fmaf(a1.z, b1.z, acc0);
  acc0 = fmaf(a1.w, b1.w, acc0);
  float acc1 = a0.x * c0.x;
  acc1 = fmaf(a0.y, c0.y, acc1);
  acc1 = fmaf(a0.z, c0.z, acc1);
  acc1 = fmaf(a0.w, c0.w, acc1);
  acc1 = fmaf(a1.x, c1.x, acc1);
  acc1 = fmaf(a1.y, c1.y, acc1);
  acc1 = fmaf(a1.z, c1.z, acc1);
  acc1 = fmaf(a1.w, c1.w, acc1);
  acc0 = waveReduceSum(acc0);
  acc1 = waveReduceSum(acc1);
  if (lane == 0) {
    outp[0] = acc0 + bias0;
    outp[1] = acc1 + bias1;
  }
}

// ---------------------------------------------------------------------------
// Kernel 2: mega2. grid = 256 (TWO blocks per batch b), block = 1024.
// Block (b, half) sims rows [half*1024, +1024) -> LDS + global (atomic agent
// stores). One flag handshake with partner block, partner half pulled via
// cache-bypassing relaxed agent atomic loads. Attention computed redundantly
// (identical inputs -> bitwise identical) in both blocks, fully in LDS.
// Phase C updates this block's own half (same-CU warm mem rows); rv via
// 2-partial atomicAdd.
// ---------------------------------------------------------------------------
__global__ __launch_bounds__(1024) void mega2_kernel(
    const float* __restrict__ mem, const float* __restrict__ ra,
    const float* __restrict__ wa, const float* __restrict__ pr,
    const float* __restrict__ pw, float* __restrict__ simg,
    int* __restrict__ flags, float* __restrict__ rv,
    float* __restrict__ nmem) {
  __shared__ float sims[3][A_];              // 24 KB
  __shared__ float wg[A_];                   // 8 KB
  __shared__ __align__(16) float qs[3 * C_]; // 1.5 KB
  __shared__ float iqn[3];
  __shared__ float rbuf[16];
  __shared__ float4 red[2][16][32];          // 16 KB

  int bid = blockIdx.x;
  int b = bid >> 1;
  int half = bid & 1;
  int rowbase = half << 10;                  // 0 or 1024
  int tid = threadIdx.x;
  int lane = tid & 63;
  int wv = tid >> 6;                         // 0..15

  // ---- q-prep: sigmoid + inverse norms
  if (tid < 3 * C_) {
    int hd = tid >> 7;
    int c = tid & (C_ - 1);
    float raw = (hd < 2) ? pr[(size_t)(hd * B_ + b) * PR_ + c]
                         : pw[(size_t)b * PW_ + c];
    qs[tid] = sigmoidf_(raw);
  }
  __syncthreads();
  if (wv < 3) {
    float v0 = qs[wv * C_ + lane];
    float v1 = qs[wv * C_ + 64 + lane];
    float ss = v0 * v0 + v1 * v1;
    ss = waveReduceSum(ss);
    if (lane == 0) iqn[wv] = 1.0f / fmaxf(sqrtf(ss), 1e-8f);
  }
  __syncthreads();

  // ---- Phase A: sim over own 1024 rows. 8 lanes/row; 128 rows/pass; 8 passes.
  {
    int j = tid & 7;
    int rgrp = tid >> 3;                     // 0..127
    float4 q0[4], q1[4], q2[4];
    const float4* qs4 = (const float4*)qs;
#pragma unroll
    for (int k = 0; k < 4; k++) {
      q0[k] = qs4[j + 8 * k];
      q1[k] = qs4[32 + j + 8 * k];
      q2[k] = qs4[64 + j + 8 * k];
    }
    float iq0 = iqn[0], iq1 = iqn[1], iq2 = iqn[2];
#pragma unroll 2
    for (int i = 0; i < 8; i++) {
      int row = rowbase + (i << 7) + rgrp;
      const float4* mrow = (const float4*)(mem + ((size_t)b * A_ + row) * C_);
      float d0 = 0.f, d1 = 0.f, d2 = 0.f, ss = 0.f;
#pragma unroll
      for (int k = 0; k < 4; k++) {
        float4 m = mrow[j + 8 * k];
        d0 = fmaf(m.x, q0[k].x, d0); d0 = fmaf(m.y, q0[k].y, d0);
        d0 = fmaf(m.z, q0[k].z, d0); d0 = fmaf(m.w, q0[k].w, d0);
        d1 = fmaf(m.x, q1[k].x, d1); d1 = fmaf(m.y, q1[k].y, d1);
        d1 = fmaf(m.z, q1[k].z, d1); d1 = fmaf(m.w, q1[k].w, d1);
        d2 = fmaf(m.x, q2[k].x, d2); d2 = fmaf(m.y, q2[k].y, d2);
        d2 = fmaf(m.z, q2[k].z, d2); d2 = fmaf(m.w, q2[k].w, d2);
        ss = fmaf(m.x, m.x, ss); ss = fmaf(m.y, m.y, ss);
        ss = fmaf(m.z, m.z, ss); ss = fmaf(m.w, m.w, ss);
      }
#pragma unroll
      for (int off = 1; off <= 4; off <<= 1) {
        d0 += __shfl_xor(d0, off, 64);
        d1 += __shfl_xor(d1, off, 64);
        d2 += __shfl_xor(d2, off, 64);
        ss += __shfl_xor(ss, off, 64);
      }
      if (j == 0) {
        float imn = 1.0f / fmaxf(sqrtf(ss), 1e-8f);
        float v0 = d0 * iq0 * imn;
        float v1 = d1 * iq1 * imn;
        float v2 = d2 * iq2 * imn;
        sims[0][row] = v0;
        sims[1][row] = v1;
        sims[2][row] = v2;
        __hip_atomic_store(&simg[(size_t)(0 * B_ + b) * A_ + row], v0,
                           __ATOMIC_RELAXED, __HIP_MEMORY_SCOPE_AGENT);
        __hip_atomic_store(&simg[(size_t)(1 * B_ + b) * A_ + row], v1,
                           __ATOMIC_RELAXED, __HIP_MEMORY_SCOPE_AGENT);
        __hip_atomic_store(&simg[(size_t)(2 * B_ + b) * A_ + row], v2,
                           __ATOMIC_RELAXED, __HIP_MEMORY_SCOPE_AGENT);
      }
    }
  }
  __syncthreads();

  // ---- Pair handshake: publish own flag, wait for partner's.
  if (tid == 0) {
    __hip_atomic_store(&flags[bid], 1, __ATOMIC_RELEASE, __HIP_MEMORY_SCOPE_AGENT);
    while (__hip_atomic_load(&flags[bid ^ 1], __ATOMIC_ACQUIRE,
                             __HIP_MEMORY_SCOPE_AGENT) == 0) {
      __builtin_amdgcn_s_sleep(8);
    }
  }
  __syncthreads();

  // ---- Pull partner half (cache-bypassing relaxed agent atomic loads).
  {
    int prow = (half ^ 1) << 10;
    for (int idx = tid; idx < 3 * 1024; idx += 1024) {
      int hd = idx >> 10;
      int r = idx & 1023;
      sims[hd][prow + r] =
          __hip_atomic_load(&simg[(size_t)(hd * B_ + b) * A_ + prow + r],
                            __ATOMIC_RELAXED, __HIP_MEMORY_SCOPE_AGENT);
    }
  }
  __syncthreads();

  // ---- Phase B: attention per head, fully in LDS (2 elems/thread).
  // Redundantly computed by both blocks of the pair (identical results).
  for (int hd = 0; hd < 3; hd++) {
    const float* src = (hd < 2) ? (pr + (size_t)(hd * B_ + b) * PR_)
                                : (pw + (size_t)b * PW_);
    float braw = src[C_];
    float graw = src[C_ + 1];
    float s0r = src[C_ + 2], s1r = src[C_ + 3], s2r = src[C_ + 4];
    float gmraw = src[C_ + 5];
    float mx3 = fmaxf(s0r, fmaxf(s1r, s2r));
    float e0 = expf(s0r - mx3), e1 = expf(s1r - mx3), e2 = expf(s2r - mx3);
    float sinv = 1.0f / (e0 + e1 + e2);
    float beta = softplusf_(braw) + 1.0f;
    float gate = sigmoidf_(graw);
    float sw0 = e0 * sinv, sw1 = e1 * sinv, sw2 = e2 * sinv;
    float gamma = softplusf_(gmraw) + 1.0f;
    const float* prev = (hd < 2) ? (ra + (size_t)(hd * B_ + b) * A_)
                                 : (wa + (size_t)b * A_);

    float s0 = sims[hd][tid];
    float s1 = sims[hd][tid + 1024];
    float pv0 = prev[tid];
    float pv1 = prev[tid + 1024];

    float mx = fmaxf(s0, s1);
    mx = waveReduceMax(mx);
    if (lane == 0) rbuf[wv] = mx;
    __syncthreads();
    float M = rbuf[0];
#pragma unroll
    for (int i = 1; i < 16; i++) M = fmaxf(M, rbuf[i]);
    __syncthreads();

    float p0 = expf(beta * (s0 - M));
    float p1 = expf(beta * (s1 - M));
    float l = p0 + p1;
    l = waveReduceSum(l);
    if (lane == 0) rbuf[wv] = l;
    __syncthreads();
    float T = rbuf[0];
#pragma unroll
    for (int i = 1; i < 16; i++) T += rbuf[i];
    float inv = 1.0f / T;

    wg[tid] = fmaf(gate, p0 * inv, (1.0f - gate) * pv0);
    wg[tid + 1024] = fmaf(gate, p1 * inv, (1.0f - gate) * pv1);
    __syncthreads();

    float ws0 = sw0 * wg[(tid + 1) & (A_ - 1)] + sw1 * wg[tid] +
                sw2 * wg[(tid - 1) & (A_ - 1)];
    float ws1 = sw0 * wg[(tid + 1025) & (A_ - 1)] + sw1 * wg[tid + 1024] +
                sw2 * wg[(tid + 1023) & (A_ - 1)];
    float wp0 = (ws0 > 0.0f) ? exp2f(gamma * log2f(ws0)) : 0.0f;
    float wp1 = (ws1 > 0.0f) ? exp2f(gamma * log2f(ws1)) : 0.0f;
    float l2 = wp0 + wp1;
    l2 = waveReduceSum(l2);
    __syncthreads();                 // all rbuf reads (T) done before rewrite
    if (lane == 0) rbuf[wv] = l2;
    __syncthreads();
    float T2 = rbuf[0];
#pragma unroll
    for (int i = 1; i < 16; i++) T2 += rbuf[i];
    float inv2 = 1.0f / (T2 + 1e-12f);
    sims[hd][tid] = wp0 * inv2;
    sims[hd][tid + 1024] = wp1 * inv2;
    __syncthreads();                 // protect rbuf/wg for next head
  }

  // ---- Phase C: update own 1024 rows. 32 lanes/row (quad c0), 32 passes.
  {
    int quad = tid & 31;
    int rgrp = tid >> 5;                     // 0..31
    int c0 = quad << 2;
    const float* pwrow = pw + (size_t)b * PW_;
    float2 eA = *(const float2*)(pwrow + C_ + 6 + c0);
    float2 eB = *(const float2*)(pwrow + C_ + 6 + c0 + 2);
    float2 aA = *(const float2*)(pwrow + 2 * C_ + 6 + c0);
    float2 aB = *(const float2*)(pwrow + 2 * C_ + 6 + c0 + 2);
    float e0 = sigmoidf_(eA.x), e1 = sigmoidf_(eA.y), e2 = sigmoidf_(eB.x), e3 = sigmoidf_(eB.y);
    float ad0 = sigmoidf_(aA.x), ad1 = sigmoidf_(aA.y), ad2 = sigmoidf_(aB.x), ad3 = sigmoidf_(aB.y);

    float4 acc0 = make_float4(0.f, 0.f, 0.f, 0.f);
    float4 acc1 = make_float4(0.f, 0.f, 0.f, 0.f);

#pragma unroll 4
    for (int i = 0; i < 32; i++) {
      int row = rowbase + (i << 5) + rgrp;
      size_t base = ((size_t)b * A_ + row) * C_ + c0;
      float4 m = *(const float4*)(mem + base);
      float w0 = sims[0][row];
      float w1 = sims[1][row];
      float ww = sims[2][row];
      acc0.x = fmaf(w0, m.x, acc0.x);
      acc0.y = fmaf(w0, m.y, acc0.y);
      acc0.z = fmaf(w0, m.z, acc0.z);
      acc0.w = fmaf(w0, m.w, acc0.w);
      acc1.x = fmaf(w1, m.x, acc1.x);
      acc1.y = fmaf(w1, m.y, acc1.y);
      acc1.z = fmaf(w1, m.z, acc1.z);
      acc1.w = fmaf(w1, m.w, acc1.w);
      vfloat4 nm;
      nm.x = fmaf(m.x, 1.0f - ww * e0, ww * ad0);
      nm.y = fmaf(m.y, 1.0f - ww * e1, ww * ad1);
      nm.z = fmaf(m.z, 1.0f - ww * e2, ww * ad2);
      nm.w = fmaf(m.w, 1.0f - ww * e3, ww * ad3);
      __builtin_nontemporal_store(nm, (vfloat4*)(nmem + base));
    }

    // fold rgrp pairs within each wave (lanes 32 apart share quad)
    acc0.x += __shfl_xor(acc0.x, 32, 64);
    acc0.y += __shfl_xor(acc0.y, 32, 64);
    acc0.z += __shfl_xor(acc0.z, 32, 64);
    acc0.w += __shfl_xor(acc0.w, 32, 64);
    acc1.x += __shfl_xor(acc1.x, 32, 64);
    acc1.y += __shfl_xor(acc1.y, 32, 64);
    acc1.z += __shfl_xor(acc1.z, 32, 64);
    acc1.w += __shfl_xor(acc1.w, 32, 64);
    if (lane < 32) {
      red[0][wv][lane] = acc0;
      red[1][wv][lane] = acc1;
    }
    __syncthreads();
    if (tid < 64) {
      int hd = tid >> 5;
      int q = tid & 31;
      float4 r = red[hd][0][q];
#pragma unroll
      for (int g = 1; g < 16; g++) {
        float4 t = red[hd][g][q];
        r.x += t.x; r.y += t.y; r.z += t.z; r.w += t.w;
      }
      float* rvp = rv + (size_t)(hd * B_ + b) * C_ + (q << 2);
      atomicAdd(rvp + 0, r.x);
      atomicAdd(rvp + 1, r.y);
      atomicAdd(rvp + 2, r.z);
      atomicAdd(rvp + 3, r.w);
    }
  }
}

extern "C" void kernel_launch(void* const* d_in, const int* in_sizes, int n_in,
                              void* d_out, int out_size, void* d_ws, size_t ws_size,
                              hipStream_t stream) {
  const float* h   = (const float*)d_in[0];
  const float* mem = (const float*)d_in[1];
  const float* ra  = (const float*)d_in[2];
  const float* wa  = (const float*)d_in[3];
  const float* Wr  = (const float*)d_in[4];
  const float* br  = (const float*)d_in[5];
  const float* Ww  = (const float*)d_in[6];
  const float* bw  = (const float*)d_in[7];

  float* out = (float*)d_out;
  float* rv = out;                               // [NR][B][C]
  float* nmem = out + NR_ * B_ * C_;             // [B][A][C]

  float* ws = (float*)d_ws;
  float* pr_buf = ws;                            // NR*B*PR = 34304
  float* pw_buf = pr_buf + NR_ * B_ * PR_;       // B*PW    = 49920
  float* simg   = pw_buf + B_ * PW_;             // 3*B*A   = 786432
  int*   flags  = (int*)(simg + 3 * B_ * A_);    // 256

  constexpr int NPAIRS = (NR_ * B_ * PR_ + B_ * PW_) / 2;  // 42112 waves
  proj_kernel<<<dim3(NPAIRS / 4), dim3(256), 0, stream>>>(h, Wr, br, Ww, bw,
                                                          pr_buf, pw_buf, rv, flags);
  mega2_kernel<<<dim3(2 * B_), dim3(1024), 0, stream>>>(mem, ra, wa, pr_buf,
                                                        pw_buf, simg, flags, rv, nmem);
}

// Round 6
// 303.682 us; speedup vs baseline: 1.0179x; 1.0179x over previous
//
#include <hip/hip_runtime.h>
#include <math.h>

constexpr int B_  = 128;
constexpr int A_  = 2048;
constexpr int C_  = 128;
constexpr int H_  = 512;
constexpr int S_  = 3;
constexpr int NR_ = 2;
constexpr int PR_ = C_ + 3 + S_;      // 134
constexpr int PW_ = 3 * C_ + 3 + S_;  // 390

typedef float vfloat4 __attribute__((ext_vector_type(4)));

__device__ __forceinline__ float sigmoidf_(float x) { return 1.0f / (1.0f + expf(-x)); }
__device__ __forceinline__ float softplusf_(float x) {
  return fmaxf(x, 0.0f) + log1pf(expf(-fabsf(x)));
}

__device__ __forceinline__ float waveReduceSum(float v) {
#pragma unroll
  for (int off = 32; off; off >>= 1) v += __shfl_xor(v, off, 64);
  return v;
}
__device__ __forceinline__ float waveReduceMax(float v) {
#pragma unroll
  for (int off = 32; off; off >>= 1) v = fmaxf(v, __shfl_xor(v, off, 64));
  return v;
}

__device__ __forceinline__ float dot8_(float4 a0, float4 a1, float4 b0, float4 b1) {
  float acc = a0.x * b0.x;
  acc = fmaf(a0.y, b0.y, acc);
  acc = fmaf(a0.z, b0.z, acc);
  acc = fmaf(a0.w, b0.w, acc);
  acc = fmaf(a1.x, b1.x, acc);
  acc = fmaf(a1.y, b1.y, acc);
  acc = fmaf(a1.z, b1.z, acc);
  acc = fmaf(a1.w, b1.w, acc);
  return acc;
}

// LDS layouts for the two roles (a block is entirely one role; union reuse).
// Member order keeps every float4-accessed array 16B-aligned.
struct SmemR {
  float4 red[2][16][32];        // 16384 B (rv reduction)
  float sims[2][A_];            // 16384 B
  float wg[A_];                 //  8192 B
  alignas(16) float praw[2 * PR_];  // 1072 B
  alignas(16) float qs[2][C_];  // 1024 B (float4-read)
  float iqn[2];
  float rbuf[16];
};
struct SmemW {
  alignas(16) float qs[C_];     // 512 B (float4-read)
  float sims[A_];               // 8192 B
  float wg[A_];                 // 8192 B
  float praw[PW_];              // 1560 B
  float iqn1;
  float rbuf[16];
};
union __align__(16) Smem {
  SmemR r;
  SmemW w;
};

// ---------------------------------------------------------------------------
// Single fused kernel. grid = 2*B = 256 blocks (one per CU), block = 1024.
// Block (2b):   R-role  — proj heads 0,1 -> sim -> attn x2 -> rv.
// Block (2b+1): W-role  — proj write head -> sim -> attn -> nmem update.
// No inter-block communication of any kind.
// ---------------------------------------------------------------------------
__global__ __launch_bounds__(1024) void fused_kernel(
    const float* __restrict__ h, const float* __restrict__ mem,
    const float* __restrict__ ra, const float* __restrict__ wa,
    const float* __restrict__ Wr, const float* __restrict__ br,
    const float* __restrict__ Ww, const float* __restrict__ bw,
    float* __restrict__ rv, float* __restrict__ nmem) {
  __shared__ Smem sm;

  int bid = blockIdx.x;
  int b = bid >> 1;
  int tid = threadIdx.x;
  int lane = tid & 63;
  int wv = tid >> 6;                         // 0..15

  // h fragment for this lane (same for every proj pass)
  const float4* h4 = (const float4*)(h + (size_t)b * H_);
  float4 a0 = h4[lane << 1];
  float4 a1 = h4[(lane << 1) + 1];

  if ((bid & 1) == 0) {
    // ===================== R role: read heads 0,1 =====================
    // ---- proj: 268 outputs, one wave per 2 adjacent (PR_=134 even: no straddle)
#pragma unroll
    for (int pass = 0; pass < 9; ++pass) {
      int out0 = pass * 32 + (wv << 1);
      if (out0 < 2 * PR_) {
        int hd = out0 >= PR_;
        int p = out0 - hd * PR_;
        const float4* w04 = (const float4*)(Wr + (size_t)(hd * PR_ + p) * H_);
        const float4* w14 = (const float4*)(Wr + (size_t)(hd * PR_ + p + 1) * H_);
        float4 b0 = w04[lane << 1];
        float4 b1 = w04[(lane << 1) + 1];
        float4 c0 = w14[lane << 1];
        float4 c1 = w14[(lane << 1) + 1];
        float acc0 = waveReduceSum(dot8_(a0, a1, b0, b1));
        float acc1 = waveReduceSum(dot8_(a0, a1, c0, c1));
        if (lane == 0) {
          sm.r.praw[out0] = acc0 + br[hd * PR_ + p];
          sm.r.praw[out0 + 1] = acc1 + br[hd * PR_ + p + 1];
        }
      }
    }
    __syncthreads();

    // ---- q-prep
    if (tid < 2 * C_) {
      int hd = tid >> 7;
      int c = tid & (C_ - 1);
      sm.r.qs[hd][c] = sigmoidf_(sm.r.praw[hd * PR_ + c]);
    }
    __syncthreads();
    if (wv < 2) {
      float v0 = sm.r.qs[wv][lane];
      float v1 = sm.r.qs[wv][64 + lane];
      float ss = waveReduceSum(v0 * v0 + v1 * v1);
      if (lane == 0) sm.r.iqn[wv] = 1.0f / fmaxf(sqrtf(ss), 1e-8f);
    }
    __syncthreads();

    // ---- sim heads 0,1 over all rows. 8 lanes/row; 128 rows/pass; 16 passes.
    {
      int j = tid & 7;
      int rgrp = tid >> 3;                   // 0..127
      float4 q0[4], q1[4];
      const float4* q04 = (const float4*)sm.r.qs[0];
      const float4* q14 = (const float4*)sm.r.qs[1];
#pragma unroll
      for (int k = 0; k < 4; k++) {
        q0[k] = q04[j + 8 * k];
        q1[k] = q14[j + 8 * k];
      }
      float iq0 = sm.r.iqn[0], iq1 = sm.r.iqn[1];
#pragma unroll 2
      for (int i = 0; i < 16; i++) {
        int row = (i << 7) + rgrp;
        const float4* mrow = (const float4*)(mem + ((size_t)b * A_ + row) * C_);
        float d0 = 0.f, d1 = 0.f, ss = 0.f;
#pragma unroll
        for (int k = 0; k < 4; k++) {
          float4 m = mrow[j + 8 * k];
          d0 = fmaf(m.x, q0[k].x, d0); d0 = fmaf(m.y, q0[k].y, d0);
          d0 = fmaf(m.z, q0[k].z, d0); d0 = fmaf(m.w, q0[k].w, d0);
          d1 = fmaf(m.x, q1[k].x, d1); d1 = fmaf(m.y, q1[k].y, d1);
          d1 = fmaf(m.z, q1[k].z, d1); d1 = fmaf(m.w, q1[k].w, d1);
          ss = fmaf(m.x, m.x, ss); ss = fmaf(m.y, m.y, ss);
          ss = fmaf(m.z, m.z, ss); ss = fmaf(m.w, m.w, ss);
        }
#pragma unroll
        for (int off = 1; off <= 4; off <<= 1) {
          d0 += __shfl_xor(d0, off, 64);
          d1 += __shfl_xor(d1, off, 64);
          ss += __shfl_xor(ss, off, 64);
        }
        if (j == 0) {
          float imn = 1.0f / fmaxf(sqrtf(ss), 1e-8f);
          sm.r.sims[0][row] = d0 * iq0 * imn;
          sm.r.sims[1][row] = d1 * iq1 * imn;
        }
      }
    }
    __syncthreads();

    // ---- attention heads 0,1 fully in LDS (2 elems/thread).
    for (int hd = 0; hd < 2; hd++) {
      float braw = sm.r.praw[hd * PR_ + C_];
      float graw = sm.r.praw[hd * PR_ + C_ + 1];
      float s0r = sm.r.praw[hd * PR_ + C_ + 2];
      float s1r = sm.r.praw[hd * PR_ + C_ + 3];
      float s2r = sm.r.praw[hd * PR_ + C_ + 4];
      float gmraw = sm.r.praw[hd * PR_ + C_ + 5];
      float mx3 = fmaxf(s0r, fmaxf(s1r, s2r));
      float e0 = expf(s0r - mx3), e1 = expf(s1r - mx3), e2 = expf(s2r - mx3);
      float sinv = 1.0f / (e0 + e1 + e2);
      float beta = softplusf_(braw) + 1.0f;
      float gate = sigmoidf_(graw);
      float sw0 = e0 * sinv, sw1 = e1 * sinv, sw2 = e2 * sinv;
      float gamma = softplusf_(gmraw) + 1.0f;
      const float* prev = ra + (size_t)(hd * B_ + b) * A_;

      float s0 = sm.r.sims[hd][tid];
      float s1 = sm.r.sims[hd][tid + 1024];
      float pv0 = prev[tid];
      float pv1 = prev[tid + 1024];

      float mx = waveReduceMax(fmaxf(s0, s1));
      if (lane == 0) sm.r.rbuf[wv] = mx;
      __syncthreads();
      float M = sm.r.rbuf[0];
#pragma unroll
      for (int i = 1; i < 16; i++) M = fmaxf(M, sm.r.rbuf[i]);
      __syncthreads();

      float p0 = expf(beta * (s0 - M));
      float p1 = expf(beta * (s1 - M));
      float l = waveReduceSum(p0 + p1);
      if (lane == 0) sm.r.rbuf[wv] = l;
      __syncthreads();
      float T = sm.r.rbuf[0];
#pragma unroll
      for (int i = 1; i < 16; i++) T += sm.r.rbuf[i];
      float inv = 1.0f / T;

      sm.r.wg[tid] = fmaf(gate, p0 * inv, (1.0f - gate) * pv0);
      sm.r.wg[tid + 1024] = fmaf(gate, p1 * inv, (1.0f - gate) * pv1);
      __syncthreads();

      float ws0 = sw0 * sm.r.wg[(tid + 1) & (A_ - 1)] + sw1 * sm.r.wg[tid] +
                  sw2 * sm.r.wg[(tid - 1) & (A_ - 1)];
      float ws1 = sw0 * sm.r.wg[(tid + 1025) & (A_ - 1)] + sw1 * sm.r.wg[tid + 1024] +
                  sw2 * sm.r.wg[(tid + 1023) & (A_ - 1)];
      float wp0 = (ws0 > 0.0f) ? exp2f(gamma * log2f(ws0)) : 0.0f;
      float wp1 = (ws1 > 0.0f) ? exp2f(gamma * log2f(ws1)) : 0.0f;
      float l2 = waveReduceSum(wp0 + wp1);
      __syncthreads();               // all T reads done before rbuf rewrite
      if (lane == 0) sm.r.rbuf[wv] = l2;
      __syncthreads();
      float T2 = sm.r.rbuf[0];
#pragma unroll
      for (int i = 1; i < 16; i++) T2 += sm.r.rbuf[i];
      float inv2 = 1.0f / (T2 + 1e-12f);
      sm.r.sims[hd][tid] = wp0 * inv2;
      sm.r.sims[hd][tid + 1024] = wp1 * inv2;
      __syncthreads();               // protect rbuf/wg for next head / rv phase
    }

    // ---- rv pass: 32 lanes/row (quad c0), 64 rows/thread; direct store.
    {
      int quad = tid & 31;
      int rgrp = tid >> 5;                   // 0..31
      int c0 = quad << 2;
      float4 acc0 = make_float4(0.f, 0.f, 0.f, 0.f);
      float4 acc1 = make_float4(0.f, 0.f, 0.f, 0.f);
#pragma unroll 4
      for (int i = 0; i < 64; i++) {
        int row = (i << 5) + rgrp;
        size_t base = ((size_t)b * A_ + row) * C_ + c0;
        float4 m = *(const float4*)(mem + base);
        float w0 = sm.r.sims[0][row];
        float w1 = sm.r.sims[1][row];
        acc0.x = fmaf(w0, m.x, acc0.x);
        acc0.y = fmaf(w0, m.y, acc0.y);
        acc0.z = fmaf(w0, m.z, acc0.z);
        acc0.w = fmaf(w0, m.w, acc0.w);
        acc1.x = fmaf(w1, m.x, acc1.x);
        acc1.y = fmaf(w1, m.y, acc1.y);
        acc1.z = fmaf(w1, m.z, acc1.z);
        acc1.w = fmaf(w1, m.w, acc1.w);
      }
      acc0.x += __shfl_xor(acc0.x, 32, 64);
      acc0.y += __shfl_xor(acc0.y, 32, 64);
      acc0.z += __shfl_xor(acc0.z, 32, 64);
      acc0.w += __shfl_xor(acc0.w, 32, 64);
      acc1.x += __shfl_xor(acc1.x, 32, 64);
      acc1.y += __shfl_xor(acc1.y, 32, 64);
      acc1.z += __shfl_xor(acc1.z, 32, 64);
      acc1.w += __shfl_xor(acc1.w, 32, 64);
      if (lane < 32) {
        sm.r.red[0][wv][lane] = acc0;
        sm.r.red[1][wv][lane] = acc1;
      }
      __syncthreads();
      if (tid < 64) {
        int hd = tid >> 5;
        int q = tid & 31;
        float4 r = sm.r.red[hd][0][q];
#pragma unroll
        for (int g = 1; g < 16; g++) {
          float4 t = sm.r.red[hd][g][q];
          r.x += t.x; r.y += t.y; r.z += t.z; r.w += t.w;
        }
        float* rvp = rv + (size_t)(hd * B_ + b) * C_ + (q << 2);
        rvp[0] = r.x;
        rvp[1] = r.y;
        rvp[2] = r.z;
        rvp[3] = r.w;
      }
    }
  } else {
    // ===================== W role: write head =====================
    // ---- proj: 390 outputs (PW_ even: pairs never straddle)
#pragma unroll
    for (int pass = 0; pass < 13; ++pass) {
      int out0 = pass * 32 + (wv << 1);
      if (out0 < PW_) {
        const float4* w04 = (const float4*)(Ww + (size_t)out0 * H_);
        const float4* w14 = (const float4*)(Ww + (size_t)(out0 + 1) * H_);
        float4 b0 = w04[lane << 1];
        float4 b1 = w04[(lane << 1) + 1];
        float4 c0 = w14[lane << 1];
        float4 c1 = w14[(lane << 1) + 1];
        float acc0 = waveReduceSum(dot8_(a0, a1, b0, b1));
        float acc1 = waveReduceSum(dot8_(a0, a1, c0, c1));
        if (lane == 0) {
          sm.w.praw[out0] = acc0 + bw[out0];
          sm.w.praw[out0 + 1] = acc1 + bw[out0 + 1];
        }
      }
    }
    __syncthreads();

    // ---- q-prep
    if (tid < C_) sm.w.qs[tid] = sigmoidf_(sm.w.praw[tid]);
    __syncthreads();
    if (wv == 0) {
      float v0 = sm.w.qs[lane];
      float v1 = sm.w.qs[64 + lane];
      float ss = waveReduceSum(v0 * v0 + v1 * v1);
      if (lane == 0) sm.w.iqn1 = 1.0f / fmaxf(sqrtf(ss), 1e-8f);
    }
    __syncthreads();

    // ---- sim head 2. 8 lanes/row; 128 rows/pass; 16 passes.
    {
      int j = tid & 7;
      int rgrp = tid >> 3;
      float4 q2[4];
      const float4* q24 = (const float4*)sm.w.qs;
#pragma unroll
      for (int k = 0; k < 4; k++) q2[k] = q24[j + 8 * k];
      float iq2 = sm.w.iqn1;
#pragma unroll 2
      for (int i = 0; i < 16; i++) {
        int row = (i << 7) + rgrp;
        const float4* mrow = (const float4*)(mem + ((size_t)b * A_ + row) * C_);
        float d2 = 0.f, ss = 0.f;
#pragma unroll
        for (int k = 0; k < 4; k++) {
          float4 m = mrow[j + 8 * k];
          d2 = fmaf(m.x, q2[k].x, d2); d2 = fmaf(m.y, q2[k].y, d2);
          d2 = fmaf(m.z, q2[k].z, d2); d2 = fmaf(m.w, q2[k].w, d2);
          ss = fmaf(m.x, m.x, ss); ss = fmaf(m.y, m.y, ss);
          ss = fmaf(m.z, m.z, ss); ss = fmaf(m.w, m.w, ss);
        }
#pragma unroll
        for (int off = 1; off <= 4; off <<= 1) {
          d2 += __shfl_xor(d2, off, 64);
          ss += __shfl_xor(ss, off, 64);
        }
        if (j == 0) {
          float imn = 1.0f / fmaxf(sqrtf(ss), 1e-8f);
          sm.w.sims[row] = d2 * iq2 * imn;
        }
      }
    }
    __syncthreads();

    // ---- attention (write head), fully in LDS.
    {
      float braw = sm.w.praw[C_];
      float graw = sm.w.praw[C_ + 1];
      float s0r = sm.w.praw[C_ + 2];
      float s1r = sm.w.praw[C_ + 3];
      float s2r = sm.w.praw[C_ + 4];
      float gmraw = sm.w.praw[C_ + 5];
      float mx3 = fmaxf(s0r, fmaxf(s1r, s2r));
      float e0 = expf(s0r - mx3), e1 = expf(s1r - mx3), e2 = expf(s2r - mx3);
      float sinv = 1.0f / (e0 + e1 + e2);
      float beta = softplusf_(braw) + 1.0f;
      float gate = sigmoidf_(graw);
      float sw0 = e0 * sinv, sw1 = e1 * sinv, sw2 = e2 * sinv;
      float gamma = softplusf_(gmraw) + 1.0f;
      const float* prev = wa + (size_t)b * A_;

      float s0 = sm.w.sims[tid];
      float s1 = sm.w.sims[tid + 1024];
      float pv0 = prev[tid];
      float pv1 = prev[tid + 1024];

      float mx = waveReduceMax(fmaxf(s0, s1));
      if (lane == 0) sm.w.rbuf[wv] = mx;
      __syncthreads();
      float M = sm.w.rbuf[0];
#pragma unroll
      for (int i = 1; i < 16; i++) M = fmaxf(M, sm.w.rbuf[i]);
      __syncthreads();

      float p0 = expf(beta * (s0 - M));
      float p1 = expf(beta * (s1 - M));
      float l = waveReduceSum(p0 + p1);
      if (lane == 0) sm.w.rbuf[wv] = l;
      __syncthreads();
      float T = sm.w.rbuf[0];
#pragma unroll
      for (int i = 1; i < 16; i++) T += sm.w.rbuf[i];
      float inv = 1.0f / T;

      sm.w.wg[tid] = fmaf(gate, p0 * inv, (1.0f - gate) * pv0);
      sm.w.wg[tid + 1024] = fmaf(gate, p1 * inv, (1.0f - gate) * pv1);
      __syncthreads();

      float ws0 = sw0 * sm.w.wg[(tid + 1) & (A_ - 1)] + sw1 * sm.w.wg[tid] +
                  sw2 * sm.w.wg[(tid - 1) & (A_ - 1)];
      float ws1 = sw0 * sm.w.wg[(tid + 1025) & (A_ - 1)] + sw1 * sm.w.wg[tid + 1024] +
                  sw2 * sm.w.wg[(tid + 1023) & (A_ - 1)];
      float wp0 = (ws0 > 0.0f) ? exp2f(gamma * log2f(ws0)) : 0.0f;
      float wp1 = (ws1 > 0.0f) ? exp2f(gamma * log2f(ws1)) : 0.0f;
      float l2 = waveReduceSum(wp0 + wp1);
      __syncthreads();
      if (lane == 0) sm.w.rbuf[wv] = l2;
      __syncthreads();
      float T2 = sm.w.rbuf[0];
#pragma unroll
      for (int i = 1; i < 16; i++) T2 += sm.w.rbuf[i];
      float inv2 = 1.0f / (T2 + 1e-12f);
      sm.w.sims[tid] = wp0 * inv2;
      sm.w.sims[tid + 1024] = wp1 * inv2;
      __syncthreads();
    }

    // ---- update pass: nmem = mem*(1 - w*e) + w*a, NT stores.
    {
      int quad = tid & 31;
      int rgrp = tid >> 5;                   // 0..31
      int c0 = quad << 2;
      float e0 = sigmoidf_(sm.w.praw[C_ + 6 + c0]);
      float e1 = sigmoidf_(sm.w.praw[C_ + 6 + c0 + 1]);
      float e2 = sigmoidf_(sm.w.praw[C_ + 6 + c0 + 2]);
      float e3 = sigmoidf_(sm.w.praw[C_ + 6 + c0 + 3]);
      float ad0 = sigmoidf_(sm.w.praw[2 * C_ + 6 + c0]);
      float ad1 = sigmoidf_(sm.w.praw[2 * C_ + 6 + c0 + 1]);
      float ad2 = sigmoidf_(sm.w.praw[2 * C_ + 6 + c0 + 2]);
      float ad3 = sigmoidf_(sm.w.praw[2 * C_ + 6 + c0 + 3]);
#pragma unroll 4
      for (int i = 0; i < 64; i++) {
        int row = (i << 5) + rgrp;
        size_t base = ((size_t)b * A_ + row) * C_ + c0;
        float4 m = *(const float4*)(mem + base);
        float ww = sm.w.sims[row];
        vfloat4 nm;
        nm.x = fmaf(m.x, 1.0f - ww * e0, ww * ad0);
        nm.y = fmaf(m.y, 1.0f - ww * e1, ww * ad1);
        nm.z = fmaf(m.z, 1.0f - ww * e2, ww * ad2);
        nm.w = fmaf(m.w, 1.0f - ww * e3, ww * ad3);
        __builtin_nontemporal_store(nm, (vfloat4*)(nmem + base));
      }
    }
  }
}

extern "C" void kernel_launch(void* const* d_in, const int* in_sizes, int n_in,
                              void* d_out, int out_size, void* d_ws, size_t ws_size,
                              hipStream_t stream) {
  const float* h   = (const float*)d_in[0];
  const float* mem = (const float*)d_in[1];
  const float* ra  = (const float*)d_in[2];
  const float* wa  = (const float*)d_in[3];
  const float* Wr  = (const float*)d_in[4];
  const float* br  = (const float*)d_in[5];
  const float* Ww  = (const float*)d_in[6];
  const float* bw  = (const float*)d_in[7];

  float* out = (float*)d_out;
  float* rv = out;                               // [NR][B][C]
  float* nmem = out + NR_ * B_ * C_;             // [B][A][C]

  fused_kernel<<<dim3(2 * B_), dim3(1024), 0, stream>>>(h, mem, ra, wa, Wr, br,
                                                        Ww, bw, rv, nmem);
}

// Round 7
// 297.324 us; speedup vs baseline: 1.0396x; 1.0214x over previous
//
#include <hip/hip_runtime.h>
#include <math.h>

constexpr int B_  = 128;
constexpr int A_  = 2048;
constexpr int C_  = 128;
constexpr int H_  = 512;
constexpr int S_  = 3;
constexpr int NR_ = 2;
constexpr int PR_ = C_ + 3 + S_;      // 134
constexpr int PW_ = 3 * C_ + 3 + S_;  // 390

typedef float vfloat4 __attribute__((ext_vector_type(4)));

__device__ __forceinline__ float sigmoidf_(float x) { return 1.0f / (1.0f + expf(-x)); }
__device__ __forceinline__ float softplusf_(float x) {
  return fmaxf(x, 0.0f) + log1pf(expf(-fabsf(x)));
}

__device__ __forceinline__ float waveReduceSum(float v) {
#pragma unroll
  for (int off = 32; off; off >>= 1) v += __shfl_xor(v, off, 64);
  return v;
}
__device__ __forceinline__ float waveReduceMax(float v) {
#pragma unroll
  for (int off = 32; off; off >>= 1) v = fmaxf(v, __shfl_xor(v, off, 64));
  return v;
}

// ---------------------------------------------------------------------------
// Kernel 1: projections (one wave per TWO adjacent outputs) + rv zeroing.
// (Known-good from rounds 1/4/5.)
// ---------------------------------------------------------------------------
__global__ __launch_bounds__(256) void proj_kernel(
    const float* __restrict__ h, const float* __restrict__ Wr,
    const float* __restrict__ br, const float* __restrict__ Ww,
    const float* __restrict__ bw, float* __restrict__ pr, float* __restrict__ pw,
    float* __restrict__ rv) {
  constexpr int NPR = NR_ * B_ * PR_;   // 34304
  constexpr int NPW = B_ * PW_;         // 49920
  int gid = blockIdx.x * blockDim.x + threadIdx.x;
  if (gid < NR_ * B_ * C_) rv[gid] = 0.0f;
  int wave = gid >> 6;
  int lane = threadIdx.x & 63;
  int out0 = wave * 2;
  const float* w0row;
  const float* w1row;
  const float* hrow;
  float bias0, bias1;
  float* outp;
  if (out0 < NPR) {
    int r = out0 / (B_ * PR_);
    int rem = out0 - r * (B_ * PR_);
    int b = rem / PR_;
    int p = rem - b * PR_;
    w0row = Wr + (size_t)(r * PR_ + p) * H_;
    w1row = w0row + H_;
    hrow = h + (size_t)b * H_;
    bias0 = br[r * PR_ + p];
    bias1 = br[r * PR_ + p + 1];
    outp = pr + out0;
  } else {
    int w2 = out0 - NPR;
    if (w2 >= NPW) return;
    int b = w2 / PW_;
    int p = w2 - b * PW_;
    w0row = Ww + (size_t)p * H_;
    w1row = w0row + H_;
    hrow = h + (size_t)b * H_;
    bias0 = bw[p];
    bias1 = bw[p + 1];
    outp = pw + w2;
  }
  const float4* h4 = (const float4*)hrow;
  const float4* wa4 = (const float4*)w0row;
  const float4* wb4 = (const float4*)w1row;
  float4 a0 = h4[(lane << 1)];
  float4 a1 = h4[(lane << 1) + 1];
  float4 b0 = wa4[(lane << 1)];
  float4 b1 = wa4[(lane << 1) + 1];
  float4 c0 = wb4[(lane << 1)];
  float4 c1 = wb4[(lane << 1) + 1];
  float acc0 = a0.x * b0.x;
  acc0 = fmaf(a0.y, b0.y, acc0);
  acc0 = fmaf(a0.z, b0.z, acc0);
  acc0 = fmaf(a0.w, b0.w, acc0);
  acc0 = fmaf(a1.x, b1.x, acc0);
  acc0 = fmaf(a1.y, b1.y, acc0);
  acc0 = fmaf(a1.z, b1.z, acc0);
  acc0 = fmaf(a1.w, b1.w, acc0);
  float acc1 = a0.x * c0.x;
  acc1 = fmaf(a0.y, c0.y, acc1);
  acc1 = fmaf(a0.z, c0.z, acc1);
  acc1 = fmaf(a0.w, c0.w, acc1);
  acc1 = fmaf(a1.x, c1.x, acc1);
  acc1 = fmaf(a1.y, c1.y, acc1);
  acc1 = fmaf(a1.z, c1.z, acc1);
  acc1 = fmaf(a1.w, c1.w, acc1);
  acc0 = waveReduceSum(acc0);
  acc1 = waveReduceSum(acc1);
  if (lane == 0) {
    outp[0] = acc0 + bias0;
    outp[1] = acc1 + bias1;
  }
}

// ---------------------------------------------------------------------------
// Kernel 2: sim over HALF a batch per block. grid = 2*B (256), block = 1024.
// Block (b,half) streams its 1024 rows once (0.5 MB) and writes sims to
// global. Kernel boundary provides device-wide coherence for K3.
// ---------------------------------------------------------------------------
__global__ __launch_bounds__(1024) void sim_half_kernel(
    const float* __restrict__ mem, const float* __restrict__ pr,
    const float* __restrict__ pw, float* __restrict__ simg) {
  __shared__ __align__(16) float qs[3 * C_];
  __shared__ float iqn[3];

  int bid = blockIdx.x;
  int b = bid >> 1;
  int rowbase = (bid & 1) << 10;             // 0 or 1024
  int tid = threadIdx.x;
  int lane = tid & 63;
  int wv = tid >> 6;

  if (tid < 3 * C_) {
    int hd = tid >> 7;
    int c = tid & (C_ - 1);
    float raw = (hd < 2) ? pr[(size_t)(hd * B_ + b) * PR_ + c]
                         : pw[(size_t)b * PW_ + c];
    qs[tid] = sigmoidf_(raw);
  }
  __syncthreads();
  if (wv < 3) {
    float v0 = qs[wv * C_ + lane];
    float v1 = qs[wv * C_ + 64 + lane];
    float ss = waveReduceSum(v0 * v0 + v1 * v1);
    if (lane == 0) iqn[wv] = 1.0f / fmaxf(sqrtf(ss), 1e-8f);
  }
  __syncthreads();

  int j = tid & 7;
  int rgrp = tid >> 3;                       // 0..127
  float4 q0[4], q1[4], q2[4];
  const float4* qs4 = (const float4*)qs;
#pragma unroll
  for (int k = 0; k < 4; k++) {
    q0[k] = qs4[j + 8 * k];
    q1[k] = qs4[32 + j + 8 * k];
    q2[k] = qs4[64 + j + 8 * k];
  }
  float iq0 = iqn[0], iq1 = iqn[1], iq2 = iqn[2];

#pragma unroll 2
  for (int i = 0; i < 8; i++) {
    int row = rowbase + (i << 7) + rgrp;
    const float4* mrow = (const float4*)(mem + ((size_t)b * A_ + row) * C_);
    float d0 = 0.f, d1 = 0.f, d2 = 0.f, ss = 0.f;
#pragma unroll
    for (int k = 0; k < 4; k++) {
      float4 m = mrow[j + 8 * k];
      d0 = fmaf(m.x, q0[k].x, d0); d0 = fmaf(m.y, q0[k].y, d0);
      d0 = fmaf(m.z, q0[k].z, d0); d0 = fmaf(m.w, q0[k].w, d0);
      d1 = fmaf(m.x, q1[k].x, d1); d1 = fmaf(m.y, q1[k].y, d1);
      d1 = fmaf(m.z, q1[k].z, d1); d1 = fmaf(m.w, q1[k].w, d1);
      d2 = fmaf(m.x, q2[k].x, d2); d2 = fmaf(m.y, q2[k].y, d2);
      d2 = fmaf(m.z, q2[k].z, d2); d2 = fmaf(m.w, q2[k].w, d2);
      ss = fmaf(m.x, m.x, ss); ss = fmaf(m.y, m.y, ss);
      ss = fmaf(m.z, m.z, ss); ss = fmaf(m.w, m.w, ss);
    }
#pragma unroll
    for (int off = 1; off <= 4; off <<= 1) {
      d0 += __shfl_xor(d0, off, 64);
      d1 += __shfl_xor(d1, off, 64);
      d2 += __shfl_xor(d2, off, 64);
      ss += __shfl_xor(ss, off, 64);
    }
    if (j == 0) {
      float imn = 1.0f / fmaxf(sqrtf(ss), 1e-8f);
      simg[(size_t)(0 * B_ + b) * A_ + row] = d0 * iq0 * imn;
      simg[(size_t)(1 * B_ + b) * A_ + row] = d1 * iq1 * imn;
      simg[(size_t)(2 * B_ + b) * A_ + row] = d2 * iq2 * imn;
    }
  }
}

// ---------------------------------------------------------------------------
// Kernel 3: attention (redundant per half, fully in LDS from global sims)
// + update of this block's half: rv partials (atomicAdd) and nmem NT stores.
// grid = 2*B (256), block = 1024.
// ---------------------------------------------------------------------------
__global__ __launch_bounds__(1024) void attn_update_kernel(
    const float* __restrict__ mem, const float* __restrict__ ra,
    const float* __restrict__ wa, const float* __restrict__ pr,
    const float* __restrict__ pw, const float* __restrict__ simg,
    float* __restrict__ rv, float* __restrict__ nmem) {
  __shared__ float sims[3][A_];              // 24 KB
  __shared__ float wg[A_];                   // 8 KB
  __shared__ float rbuf[16];
  __shared__ float4 red[2][16][32];          // 16 KB

  int bid = blockIdx.x;
  int b = bid >> 1;
  int rowbase = (bid & 1) << 10;             // 0 or 1024
  int tid = threadIdx.x;
  int lane = tid & 63;
  int wv = tid >> 6;

  // load full-A sims for this batch (coalesced; L2/L3-hot)
#pragma unroll
  for (int k = 0; k < 6; k++) {
    int idx = k * 1024 + tid;
    int hd = idx >> 11;
    int r = idx & (A_ - 1);
    sims[hd][r] = simg[(size_t)(hd * B_ + b) * A_ + r];
  }
  __syncthreads();

  // ---- attention per head, fully in LDS (2 elems/thread).
  for (int hd = 0; hd < 3; hd++) {
    const float* src = (hd < 2) ? (pr + (size_t)(hd * B_ + b) * PR_)
                                : (pw + (size_t)b * PW_);
    float braw = src[C_];
    float graw = src[C_ + 1];
    float s0r = src[C_ + 2], s1r = src[C_ + 3], s2r = src[C_ + 4];
    float gmraw = src[C_ + 5];
    float mx3 = fmaxf(s0r, fmaxf(s1r, s2r));
    float e0 = expf(s0r - mx3), e1 = expf(s1r - mx3), e2 = expf(s2r - mx3);
    float sinv = 1.0f / (e0 + e1 + e2);
    float beta = softplusf_(braw) + 1.0f;
    float gate = sigmoidf_(graw);
    float sw0 = e0 * sinv, sw1 = e1 * sinv, sw2 = e2 * sinv;
    float gamma = softplusf_(gmraw) + 1.0f;
    const float* prev = (hd < 2) ? (ra + (size_t)(hd * B_ + b) * A_)
                                 : (wa + (size_t)b * A_);

    float s0 = sims[hd][tid];
    float s1 = sims[hd][tid + 1024];
    float pv0 = prev[tid];
    float pv1 = prev[tid + 1024];

    float mx = waveReduceMax(fmaxf(s0, s1));
    if (lane == 0) rbuf[wv] = mx;
    __syncthreads();
    float M = rbuf[0];
#pragma unroll
    for (int i = 1; i < 16; i++) M = fmaxf(M, rbuf[i]);
    __syncthreads();

    float p0 = expf(beta * (s0 - M));
    float p1 = expf(beta * (s1 - M));
    float l = waveReduceSum(p0 + p1);
    if (lane == 0) rbuf[wv] = l;
    __syncthreads();
    float T = rbuf[0];
#pragma unroll
    for (int i = 1; i < 16; i++) T += rbuf[i];
    float inv = 1.0f / T;

    wg[tid] = fmaf(gate, p0 * inv, (1.0f - gate) * pv0);
    wg[tid + 1024] = fmaf(gate, p1 * inv, (1.0f - gate) * pv1);
    __syncthreads();

    float ws0 = sw0 * wg[(tid + 1) & (A_ - 1)] + sw1 * wg[tid] +
                sw2 * wg[(tid - 1) & (A_ - 1)];
    float ws1 = sw0 * wg[(tid + 1025) & (A_ - 1)] + sw1 * wg[tid + 1024] +
                sw2 * wg[(tid + 1023) & (A_ - 1)];
    float wp0 = (ws0 > 0.0f) ? exp2f(gamma * log2f(ws0)) : 0.0f;
    float wp1 = (ws1 > 0.0f) ? exp2f(gamma * log2f(ws1)) : 0.0f;
    float l2 = waveReduceSum(wp0 + wp1);
    __syncthreads();                 // all T reads done before rbuf rewrite
    if (lane == 0) rbuf[wv] = l2;
    __syncthreads();
    float T2 = rbuf[0];
#pragma unroll
    for (int i = 1; i < 16; i++) T2 += rbuf[i];
    float inv2 = 1.0f / (T2 + 1e-12f);
    sims[hd][tid] = wp0 * inv2;
    sims[hd][tid + 1024] = wp1 * inv2;
    __syncthreads();                 // protect rbuf/wg for next head
  }

  // ---- update own half: rv partials + nmem. 32 lanes/row; 32 passes.
  {
    int quad = tid & 31;
    int rgrp = tid >> 5;                     // 0..31
    int c0 = quad << 2;
    const float* pwrow = pw + (size_t)b * PW_;
    float2 eA = *(const float2*)(pwrow + C_ + 6 + c0);
    float2 eB = *(const float2*)(pwrow + C_ + 6 + c0 + 2);
    float2 aA = *(const float2*)(pwrow + 2 * C_ + 6 + c0);
    float2 aB = *(const float2*)(pwrow + 2 * C_ + 6 + c0 + 2);
    float e0 = sigmoidf_(eA.x), e1 = sigmoidf_(eA.y), e2 = sigmoidf_(eB.x), e3 = sigmoidf_(eB.y);
    float ad0 = sigmoidf_(aA.x), ad1 = sigmoidf_(aA.y), ad2 = sigmoidf_(aB.x), ad3 = sigmoidf_(aB.y);

    float4 acc0 = make_float4(0.f, 0.f, 0.f, 0.f);
    float4 acc1 = make_float4(0.f, 0.f, 0.f, 0.f);

#pragma unroll 4
    for (int i = 0; i < 32; i++) {
      int row = rowbase + (i << 5) + rgrp;
      size_t base = ((size_t)b * A_ + row) * C_ + c0;
      float4 m = *(const float4*)(mem + base);
      float w0 = sims[0][row];
      float w1 = sims[1][row];
      float ww = sims[2][row];
      acc0.x = fmaf(w0, m.x, acc0.x);
      acc0.y = fmaf(w0, m.y, acc0.y);
      acc0.z = fmaf(w0, m.z, acc0.z);
      acc0.w = fmaf(w0, m.w, acc0.w);
      acc1.x = fmaf(w1, m.x, acc1.x);
      acc1.y = fmaf(w1, m.y, acc1.y);
      acc1.z = fmaf(w1, m.z, acc1.z);
      acc1.w = fmaf(w1, m.w, acc1.w);
      vfloat4 nm;
      nm.x = fmaf(m.x, 1.0f - ww * e0, ww * ad0);
      nm.y = fmaf(m.y, 1.0f - ww * e1, ww * ad1);
      nm.z = fmaf(m.z, 1.0f - ww * e2, ww * ad2);
      nm.w = fmaf(m.w, 1.0f - ww * e3, ww * ad3);
      __builtin_nontemporal_store(nm, (vfloat4*)(nmem + base));
    }

    acc0.x += __shfl_xor(acc0.x, 32, 64);
    acc0.y += __shfl_xor(acc0.y, 32, 64);
    acc0.z += __shfl_xor(acc0.z, 32, 64);
    acc0.w += __shfl_xor(acc0.w, 32, 64);
    acc1.x += __shfl_xor(acc1.x, 32, 64);
    acc1.y += __shfl_xor(acc1.y, 32, 64);
    acc1.z += __shfl_xor(acc1.z, 32, 64);
    acc1.w += __shfl_xor(acc1.w, 32, 64);
    if (lane < 32) {
      red[0][wv][lane] = acc0;
      red[1][wv][lane] = acc1;
    }
    __syncthreads();
    if (tid < 64) {
      int hd = tid >> 5;
      int q = tid & 31;
      float4 r = red[hd][0][q];
#pragma unroll
      for (int g = 1; g < 16; g++) {
        float4 t = red[hd][g][q];
        r.x += t.x; r.y += t.y; r.z += t.z; r.w += t.w;
      }
      float* rvp = rv + (size_t)(hd * B_ + b) * C_ + (q << 2);
      atomicAdd(rvp + 0, r.x);
      atomicAdd(rvp + 1, r.y);
      atomicAdd(rvp + 2, r.z);
      atomicAdd(rvp + 3, r.w);
    }
  }
}

extern "C" void kernel_launch(void* const* d_in, const int* in_sizes, int n_in,
                              void* d_out, int out_size, void* d_ws, size_t ws_size,
                              hipStream_t stream) {
  const float* h   = (const float*)d_in[0];
  const float* mem = (const float*)d_in[1];
  const float* ra  = (const float*)d_in[2];
  const float* wa  = (const float*)d_in[3];
  const float* Wr  = (const float*)d_in[4];
  const float* br  = (const float*)d_in[5];
  const float* Ww  = (const float*)d_in[6];
  const float* bw  = (const float*)d_in[7];

  float* out = (float*)d_out;
  float* rv = out;                               // [NR][B][C]
  float* nmem = out + NR_ * B_ * C_;             // [B][A][C]

  float* ws = (float*)d_ws;
  float* pr_buf = ws;                            // NR*B*PR = 34304
  float* pw_buf = pr_buf + NR_ * B_ * PR_;       // B*PW    = 49920
  float* simg   = pw_buf + B_ * PW_;             // 3*B*A   = 786432

  constexpr int NPAIRS = (NR_ * B_ * PR_ + B_ * PW_) / 2;  // 42112 waves
  proj_kernel<<<dim3(NPAIRS / 4), dim3(256), 0, stream>>>(h, Wr, br, Ww, bw,
                                                          pr_buf, pw_buf, rv);
  sim_half_kernel<<<dim3(2 * B_), dim3(1024), 0, stream>>>(mem, pr_buf, pw_buf, simg);
  attn_update_kernel<<<dim3(2 * B_), dim3(1024), 0, stream>>>(mem, ra, wa, pr_buf,
                                                              pw_buf, simg, rv, nmem);
}

// Round 8
// 288.632 us; speedup vs baseline: 1.0709x; 1.0301x over previous
//
#include <hip/hip_runtime.h>
#include <math.h>

constexpr int B_  = 128;
constexpr int A_  = 2048;
constexpr int C_  = 128;
constexpr int H_  = 512;
constexpr int S_  = 3;
constexpr int NR_ = 2;
constexpr int PR_ = C_ + 3 + S_;      // 134
constexpr int PW_ = 3 * C_ + 3 + S_;  // 390

typedef float vfloat4 __attribute__((ext_vector_type(4)));

__device__ __forceinline__ float sigmoidf_(float x) { return 1.0f / (1.0f + expf(-x)); }
__device__ __forceinline__ float softplusf_(float x) {
  return fmaxf(x, 0.0f) + log1pf(expf(-fabsf(x)));
}

__device__ __forceinline__ float waveReduceSum(float v) {
#pragma unroll
  for (int off = 32; off; off >>= 1) v += __shfl_xor(v, off, 64);
  return v;
}
__device__ __forceinline__ float waveReduceMax(float v) {
#pragma unroll
  for (int off = 32; off; off >>= 1) v = fmaxf(v, __shfl_xor(v, off, 64));
  return v;
}

// ---------------------------------------------------------------------------
// Kernel 1: projections. One wave per TWO adjacent output scalars (K=512 dot).
// PR (134) and PW (390) are even, and NPR is even, so both outputs of a pair
// always share the same (r,b) row -> same h row, adjacent W rows.
// Also fused: zeroing the read_vectors accumulator (first 32768 threads).
// ---------------------------------------------------------------------------
__global__ __launch_bounds__(256) void proj_kernel(
    const float* __restrict__ h, const float* __restrict__ Wr,
    const float* __restrict__ br, const float* __restrict__ Ww,
    const float* __restrict__ bw, float* __restrict__ pr, float* __restrict__ pw,
    float* __restrict__ rv) {
  constexpr int NPR = NR_ * B_ * PR_;   // 34304
  constexpr int NPW = B_ * PW_;         // 49920
  int gid = blockIdx.x * 256 + threadIdx.x;
  if (gid < NR_ * B_ * C_) rv[gid] = 0.0f;   // zero rv [NR*B*C = 32768]
  int wave = gid >> 6;
  int lane = threadIdx.x & 63;
  int out0 = wave * 2;
  const float* w0row;
  const float* w1row;
  const float* hrow;
  float bias0, bias1;
  float* outp;
  if (out0 < NPR) {
    int r = out0 / (B_ * PR_);
    int rem = out0 - r * (B_ * PR_);
    int b = rem / PR_;
    int p = rem - b * PR_;
    w0row = Wr + (size_t)(r * PR_ + p) * H_;
    w1row = w0row + H_;
    hrow = h + (size_t)b * H_;
    bias0 = br[r * PR_ + p];
    bias1 = br[r * PR_ + p + 1];
    outp = pr + out0;
  } else {
    int w2 = out0 - NPR;
    if (w2 >= NPW) return;
    int b = w2 / PW_;
    int p = w2 - b * PW_;
    w0row = Ww + (size_t)p * H_;
    w1row = w0row + H_;
    hrow = h + (size_t)b * H_;
    bias0 = bw[p];
    bias1 = bw[p + 1];
    outp = pw + w2;
  }
  const float4* h4 = (const float4*)hrow;
  const float4* wa4 = (const float4*)w0row;
  const float4* wb4 = (const float4*)w1row;
  float4 a0 = h4[(lane << 1)];
  float4 a1 = h4[(lane << 1) + 1];
  float4 b0 = wa4[(lane << 1)];
  float4 b1 = wa4[(lane << 1) + 1];
  float4 c0 = wb4[(lane << 1)];
  float4 c1 = wb4[(lane << 1) + 1];
  float acc0 = a0.x * b0.x;
  acc0 = fmaf(a0.y, b0.y, acc0);
  acc0 = fmaf(a0.z, b0.z, acc0);
  acc0 = fmaf(a0.w, b0.w, acc0);
  acc0 = fmaf(a1.x, b1.x, acc0);
  acc0 = fmaf(a1.y, b1.y, acc0);
  acc0 = fmaf(a1.z, b1.z, acc0);
  acc0 = fmaf(a1.w, b1.w, acc0);
  float acc1 = a0.x * c0.x;
  acc1 = fmaf(a0.y, c0.y, acc1);
  acc1 = fmaf(a0.z, c0.z, acc1);
  acc1 = fmaf(a0.w, c0.w, acc1);
  acc1 = fmaf(a1.x, c1.x, acc1);
  acc1 = fmaf(a1.y, c1.y, acc1);
  acc1 = fmaf(a1.z, c1.z, acc1);
  acc1 = fmaf(a1.w, c1.w, acc1);
  acc0 = waveReduceSum(acc0);
  acc1 = waveReduceSum(acc1);
  if (lane == 0) {
    outp[0] = acc0 + bias0;
    outp[1] = acc1 + bias1;
  }
}

// ---------------------------------------------------------------------------
// Kernel 2: sim pass over mem, with q-prep (sigmoid + norm) fused per block.
// 8 lanes per row; q fragments in registers; reduce = 3 shfl levels.
// grid = B * A/64 = 4096, block 256 (many small blocks stream best).
// ---------------------------------------------------------------------------
__global__ __launch_bounds__(256) void sim_kernel(
    const float* __restrict__ mem, const float* __restrict__ pr,
    const float* __restrict__ pw, float* __restrict__ sim) {
  __shared__ __align__(16) float qs[3 * C_];
  __shared__ float iqn[3];
  int b = blockIdx.x >> 5;
  int chunk = blockIdx.x & 31;
  int rowbase = chunk << 6;
  int tid = threadIdx.x;
  // q = sigmoid(raw): heads 0,1 from pr, head 2 (write) from pw
  for (int idx = tid; idx < 3 * C_; idx += 256) {
    int hd = idx >> 7;
    int c = idx & (C_ - 1);
    float raw = (hd < 2) ? pr[(size_t)(hd * B_ + b) * PR_ + c]
                         : pw[(size_t)b * PW_ + c];
    qs[idx] = sigmoidf_(raw);
  }
  __syncthreads();
  int wv = tid >> 6;
  int lane = tid & 63;
  if (wv < 3) {
    float v0 = qs[wv * C_ + lane];
    float v1 = qs[wv * C_ + 64 + lane];
    float ss = v0 * v0 + v1 * v1;
    ss = waveReduceSum(ss);
    if (lane == 0) iqn[wv] = 1.0f / fmaxf(sqrtf(ss), 1e-8f);
  }
  __syncthreads();

  int j = lane & 7;       // octet subgroup within row
  int rsub = lane >> 3;   // row within wave-iter (0..7)

  float4 q0[4], q1[4], q2[4];
  const float4* qs4 = (const float4*)qs;
#pragma unroll
  for (int k = 0; k < 4; k++) {
    q0[k] = qs4[j + 8 * k];
    q1[k] = qs4[32 + j + 8 * k];
    q2[k] = qs4[64 + j + 8 * k];
  }
  float iqn0 = iqn[0], iqn1 = iqn[1], iqn2 = iqn[2];

#pragma unroll
  for (int it = 0; it < 2; it++) {
    int row = rowbase + (it << 5) + (wv << 3) + rsub;
    const float4* mrow = (const float4*)(mem + ((size_t)b * A_ + row) * C_);
    float d0 = 0.f, d1 = 0.f, d2 = 0.f, ss = 0.f;
#pragma unroll
    for (int k = 0; k < 4; k++) {
      float4 m = mrow[j + 8 * k];
      d0 = fmaf(m.x, q0[k].x, d0); d0 = fmaf(m.y, q0[k].y, d0);
      d0 = fmaf(m.z, q0[k].z, d0); d0 = fmaf(m.w, q0[k].w, d0);
      d1 = fmaf(m.x, q1[k].x, d1); d1 = fmaf(m.y, q1[k].y, d1);
      d1 = fmaf(m.z, q1[k].z, d1); d1 = fmaf(m.w, q1[k].w, d1);
      d2 = fmaf(m.x, q2[k].x, d2); d2 = fmaf(m.y, q2[k].y, d2);
      d2 = fmaf(m.z, q2[k].z, d2); d2 = fmaf(m.w, q2[k].w, d2);
      ss = fmaf(m.x, m.x, ss); ss = fmaf(m.y, m.y, ss);
      ss = fmaf(m.z, m.z, ss); ss = fmaf(m.w, m.w, ss);
    }
#pragma unroll
    for (int off = 1; off <= 4; off <<= 1) {
      d0 += __shfl_xor(d0, off, 64);
      d1 += __shfl_xor(d1, off, 64);
      d2 += __shfl_xor(d2, off, 64);
      ss += __shfl_xor(ss, off, 64);
    }
    if (j == 0) {
      float imn = 1.0f / fmaxf(sqrtf(ss), 1e-8f);
      sim[(size_t)(0 * B_ + b) * A_ + row] = d0 * iqn0 * imn;
      sim[(size_t)(1 * B_ + b) * A_ + row] = d1 * iqn1 * imn;
      sim[(size_t)(2 * B_ + b) * A_ + row] = d2 * iqn2 * imn;
    }
  }
}

// ---------------------------------------------------------------------------
// Kernel 3: attention per (head,b). Writes IN-PLACE over sim.
// 1024 threads (2 elems/thread), scalar head params computed redundantly
// per thread from raw pr/pw (broadcast loads). grid = 3*B = 384.
// ---------------------------------------------------------------------------
__global__ __launch_bounds__(1024) void attn_kernel(
    const float* __restrict__ sim, const float* __restrict__ ra,
    const float* __restrict__ wa, const float* __restrict__ pr,
    const float* __restrict__ pw, float* __restrict__ attn) {
  __shared__ float wg[A_];
  __shared__ float rb1[16], rb2[16], rb3[16];
  int hb = blockIdx.x;
  int hd = hb >> 7;
  int b = hb & (B_ - 1);
  int tid = threadIdx.x;
  int wv = tid >> 6;
  int lane = tid & 63;
  const float* src = (hd < 2) ? (pr + (size_t)hb * PR_) : (pw + (size_t)b * PW_);
  // head scalar params: redundant per-thread compute from 6 broadcast loads
  float braw = src[C_];
  float graw = src[C_ + 1];
  float s0r = src[C_ + 2], s1r = src[C_ + 3], s2r = src[C_ + 4];
  float gmraw = src[C_ + 5];
  float mx3 = fmaxf(s0r, fmaxf(s1r, s2r));
  float e0 = expf(s0r - mx3), e1 = expf(s1r - mx3), e2 = expf(s2r - mx3);
  float sinv = 1.0f / (e0 + e1 + e2);
  float beta = softplusf_(braw) + 1.0f;
  float gate = sigmoidf_(graw);
  float sw0 = e0 * sinv, sw1 = e1 * sinv, sw2 = e2 * sinv;
  float gamma = softplusf_(gmraw) + 1.0f;

  const float* simrow = sim + (size_t)hb * A_;
  const float* prev = (hd < 2) ? (ra + (size_t)hb * A_) : (wa + (size_t)b * A_);
  float* outrow = attn + (size_t)hb * A_;

  int a0 = tid;
  int a1 = tid + 1024;
  float s0 = simrow[a0];
  float s1 = simrow[a1];
  float pv0 = prev[a0];
  float pv1 = prev[a1];

  float mx = fmaxf(s0, s1);
  mx = waveReduceMax(mx);
  if (lane == 0) rb1[wv] = mx;
  __syncthreads();
  float M = rb1[0];
#pragma unroll
  for (int i = 1; i < 16; i++) M = fmaxf(M, rb1[i]);

  float p0 = expf(beta * (s0 - M));
  float p1 = expf(beta * (s1 - M));
  float l = p0 + p1;
  l = waveReduceSum(l);
  if (lane == 0) rb2[wv] = l;
  __syncthreads();
  float T = rb2[0];
#pragma unroll
  for (int i = 1; i < 16; i++) T += rb2[i];
  float inv = 1.0f / T;

  wg[a0] = fmaf(gate, p0 * inv, (1.0f - gate) * pv0);
  wg[a1] = fmaf(gate, p1 * inv, (1.0f - gate) * pv1);
  __syncthreads();

  float ws0 = sw0 * wg[(a0 + 1) & (A_ - 1)] + sw1 * wg[a0] + sw2 * wg[(a0 - 1) & (A_ - 1)];
  float ws1 = sw0 * wg[(a1 + 1) & (A_ - 1)] + sw1 * wg[a1] + sw2 * wg[(a1 - 1) & (A_ - 1)];
  float wp0 = (ws0 > 0.0f) ? exp2f(gamma * log2f(ws0)) : 0.0f;
  float wp1 = (ws1 > 0.0f) ? exp2f(gamma * log2f(ws1)) : 0.0f;
  float l2 = wp0 + wp1;
  l2 = waveReduceSum(l2);
  if (lane == 0) rb3[wv] = l2;
  __syncthreads();
  float T2 = rb3[0];
#pragma unroll
  for (int i = 1; i < 16; i++) T2 += rb3[i];
  float inv2 = 1.0f / (T2 + 1e-12f);

  outrow[a0] = wp0 * inv2;
  outrow[a1] = wp1 * inv2;
}

// ---------------------------------------------------------------------------
// Kernel 4: second pass over mem. read_vectors + new_mem. Nontemporal stores
// for new_mem keep `mem` L3-resident for this kernel's own reads.
// Reduction: shfl_xor(32) + single-barrier 128-entry LDS fold.
// grid = B * A/256 = 1024, block 256 (many small blocks stream best).
// ---------------------------------------------------------------------------
__global__ __launch_bounds__(256) void update_kernel(
    const float* __restrict__ mem, const float* __restrict__ attn,
    const float* __restrict__ pw, float* __restrict__ rv,
    float* __restrict__ nmem) {
  __shared__ float att0[256], att1[256], attw[256];
  __shared__ float4 red0[128];
  __shared__ float4 red1[128];
  int b = blockIdx.x >> 3;
  int chunk = blockIdx.x & 7;
  int rowbase = chunk << 8;
  int tid = threadIdx.x;
  att0[tid] = attn[(size_t)(0 * B_ + b) * A_ + rowbase + tid];
  att1[tid] = attn[(size_t)(1 * B_ + b) * A_ + rowbase + tid];
  attw[tid] = attn[(size_t)(2 * B_ + b) * A_ + rowbase + tid];
  __syncthreads();

  int rowlane = tid & 31;
  int rowoff = tid >> 5;
  int c0 = rowlane << 2;
  const float* pwrow = pw + (size_t)b * PW_;
  float2 eA = *(const float2*)(pwrow + C_ + 6 + c0);        // erase at offset 134
  float2 eB = *(const float2*)(pwrow + C_ + 6 + c0 + 2);
  float2 aA = *(const float2*)(pwrow + 2 * C_ + 6 + c0);    // add at offset 262
  float2 aB = *(const float2*)(pwrow + 2 * C_ + 6 + c0 + 2);
  float e0 = sigmoidf_(eA.x), e1 = sigmoidf_(eA.y), e2 = sigmoidf_(eB.x), e3 = sigmoidf_(eB.y);
  float ad0 = sigmoidf_(aA.x), ad1 = sigmoidf_(aA.y), ad2 = sigmoidf_(aB.x), ad3 = sigmoidf_(aB.y);

  float4 acc0 = make_float4(0.f, 0.f, 0.f, 0.f);
  float4 acc1 = make_float4(0.f, 0.f, 0.f, 0.f);

#pragma unroll 4
  for (int i = 0; i < 32; i++) {
    int ridx = (i << 3) + rowoff;
    int row = rowbase + ridx;
    size_t base = ((size_t)b * A_ + row) * C_ + c0;
    float4 m = *(const float4*)(mem + base);
    float w0 = att0[ridx];
    float w1 = att1[ridx];
    float ww = attw[ridx];
    acc0.x = fmaf(w0, m.x, acc0.x);
    acc0.y = fmaf(w0, m.y, acc0.y);
    acc0.z = fmaf(w0, m.z, acc0.z);
    acc0.w = fmaf(w0, m.w, acc0.w);
    acc1.x = fmaf(w1, m.x, acc1.x);
    acc1.y = fmaf(w1, m.y, acc1.y);
    acc1.z = fmaf(w1, m.z, acc1.z);
    acc1.w = fmaf(w1, m.w, acc1.w);
    vfloat4 nm;
    nm.x = fmaf(m.x, 1.0f - ww * e0, ww * ad0);
    nm.y = fmaf(m.y, 1.0f - ww * e1, ww * ad1);
    nm.z = fmaf(m.z, 1.0f - ww * e2, ww * ad2);
    nm.w = fmaf(m.w, 1.0f - ww * e3, ww * ad3);
    __builtin_nontemporal_store(nm, (vfloat4*)(nmem + base));
  }

  // reduce over the 8 rowoffs: pair-fold via shfl (rowoff^1 within wave),
  // then 4 wave-partials folded through LDS with a single barrier.
  int lane = tid & 63;
  int wv = tid >> 6;
  acc0.x += __shfl_xor(acc0.x, 32, 64);
  acc0.y += __shfl_xor(acc0.y, 32, 64);
  acc0.z += __shfl_xor(acc0.z, 32, 64);
  acc0.w += __shfl_xor(acc0.w, 32, 64);
  acc1.x += __shfl_xor(acc1.x, 32, 64);
  acc1.y += __shfl_xor(acc1.y, 32, 64);
  acc1.z += __shfl_xor(acc1.z, 32, 64);
  acc1.w += __shfl_xor(acc1.w, 32, 64);
  if (lane < 32) {
    red0[wv * 32 + lane] = acc0;
    red1[wv * 32 + lane] = acc1;
  }
  __syncthreads();
  if (tid < 32) {
    float4 r0 = red0[tid];
    float4 t;
    t = red0[tid + 32]; r0.x += t.x; r0.y += t.y; r0.z += t.z; r0.w += t.w;
    t = red0[tid + 64]; r0.x += t.x; r0.y += t.y; r0.z += t.z; r0.w += t.w;
    t = red0[tid + 96]; r0.x += t.x; r0.y += t.y; r0.z += t.z; r0.w += t.w;
    float4 r1 = red1[tid];
    t = red1[tid + 32]; r1.x += t.x; r1.y += t.y; r1.z += t.z; r1.w += t.w;
    t = red1[tid + 64]; r1.x += t.x; r1.y += t.y; r1.z += t.z; r1.w += t.w;
    t = red1[tid + 96]; r1.x += t.x; r1.y += t.y; r1.z += t.z; r1.w += t.w;
    float* rv0 = rv + (size_t)(0 * B_ + b) * C_ + (tid << 2);
    float* rv1 = rv + (size_t)(1 * B_ + b) * C_ + (tid << 2);
    atomicAdd(rv0 + 0, r0.x);
    atomicAdd(rv0 + 1, r0.y);
    atomicAdd(rv0 + 2, r0.z);
    atomicAdd(rv0 + 3, r0.w);
    atomicAdd(rv1 + 0, r1.x);
    atomicAdd(rv1 + 1, r1.y);
    atomicAdd(rv1 + 2, r1.z);
    atomicAdd(rv1 + 3, r1.w);
  }
}

extern "C" void kernel_launch(void* const* d_in, const int* in_sizes, int n_in,
                              void* d_out, int out_size, void* d_ws, size_t ws_size,
                              hipStream_t stream) {
  const float* h   = (const float*)d_in[0];
  const float* mem = (const float*)d_in[1];
  const float* ra  = (const float*)d_in[2];
  const float* wa  = (const float*)d_in[3];
  const float* Wr  = (const float*)d_in[4];
  const float* br  = (const float*)d_in[5];
  const float* Ww  = (const float*)d_in[6];
  const float* bw  = (const float*)d_in[7];

  float* out = (float*)d_out;
  float* rv = out;                               // [NR][B][C]
  float* nmem = out + NR_ * B_ * C_;             // [B][A][C]

  float* ws = (float*)d_ws;
  float* pr_buf = ws;                            // NR*B*PR = 34304
  float* pw_buf = pr_buf + NR_ * B_ * PR_;       // B*PW    = 49920
  float* simb   = pw_buf + B_ * PW_;             // 3*B*A   = 786432 (sim, attn in-place)

  constexpr int NPAIRS = (NR_ * B_ * PR_ + B_ * PW_) / 2;  // 42112 waves
  proj_kernel<<<dim3(NPAIRS / 4), dim3(256), 0, stream>>>(h, Wr, br, Ww, bw, pr_buf, pw_buf, rv);
  sim_kernel<<<dim3(B_ * (A_ / 64)), dim3(256), 0, stream>>>(mem, pr_buf, pw_buf, simb);
  attn_kernel<<<dim3(3 * B_), dim3(1024), 0, stream>>>(simb, ra, wa, pr_buf, pw_buf, simb);
  update_kernel<<<dim3(B_ * (A_ / 256)), dim3(256), 0, stream>>>(mem, simb, pw_buf, rv, nmem);
}